// Round 10
// baseline (425.282 us; speedup 1.0000x reference)
//
#include <hip/hip_runtime.h>

#define HWDIM 48
#define NPIX 2304   // 48*48
#define CDIM 256
#define BATCH 8
#define THRESH 0.01f
#define SHIFT 90.0f
#define LISTCAP 104   // ≥ max survivors per row (≤100 since sum(S)=1, S>=0.01)

typedef _Float16 f16;
typedef _Float16 f16x8 __attribute__((ext_vector_type(8)));
typedef float f32x4 __attribute__((ext_vector_type(4)));

#define MFMA16(a, b, c) __builtin_amdgcn_mfma_f32_16x16x32_f16(a, b, c, 0, 0, 0)

static __device__ __forceinline__ unsigned short f16bits(f16 v) {
    return __builtin_bit_cast(unsigned short, v);
}
static __device__ __forceinline__ f16 bits2f16(unsigned short u) {
    return __builtin_bit_cast(f16, u);
}
// Opaque no-op: value becomes asm output -> compiler cannot re-load it from
// memory, forcing true register residency for the fragment.
static __device__ __forceinline__ void pinreg(f16x8& v) {
    asm volatile("" : "+v"(v));
}

// ---------------------------------------------------------------------------
// prep: Xh[b][n][c] = (f16)x[b][c][n]; wH = f16 casts of phi, psi, w0, w1.
// grid (72, 8, 9) block 256; z==8 handles weights.
// ---------------------------------------------------------------------------
__global__ __launch_bounds__(256) void prep_kernel(const float* __restrict__ x,
                                                   const float* __restrict__ phi,
                                                   const float* __restrict__ psi,
                                                   const float* __restrict__ w0,
                                                   const float* __restrict__ w1,
                                                   f16* __restrict__ Xh,
                                                   f16* __restrict__ wH) {
    if (blockIdx.z == BATCH) {
        int bid = blockIdx.y * gridDim.x + blockIdx.x;
        int t = bid * 256 + threadIdx.x;
        for (int i = t; i < 4 * CDIM * CDIM; i += 576 * 256) {
            const float* src = (i < 65536) ? phi : (i < 131072) ? psi
                               : (i < 196608) ? w0 : w1;
            wH[i] = (f16)src[i & 65535];
        }
        return;
    }
    __shared__ float tile[32][33];
    int b = blockIdx.z;
    int n0 = blockIdx.x * 32, c0 = blockIdx.y * 32;
    int tx = threadIdx.x & 31, ty = threadIdx.x >> 5;
    const float* xb = x + (size_t)b * CDIM * NPIX;
    f16* XhB = Xh + (size_t)b * NPIX * CDIM;
#pragma unroll
    for (int j = 0; j < 4; ++j) {
        int c = c0 + ty + 8 * j;
        tile[ty + 8 * j][tx] = xb[(size_t)c * NPIX + n0 + tx];
    }
    __syncthreads();
#pragma unroll
    for (int j = 0; j < 4; ++j) {
        int n = n0 + ty + 8 * j;
        XhB[(size_t)n * CDIM + c0 + tx] = (f16)tile[tx][ty + 8 * j];
    }
}

// ---------------------------------------------------------------------------
// proj: Qh = Xh·phiᵀ / Kh = Xh·psiᵀ. 1-D grid 576 (b = bid&7 -> XCD pinned).
// ---------------------------------------------------------------------------
__global__ __launch_bounds__(256) void proj_kernel(const f16* __restrict__ Xh,
                                                   const f16* __restrict__ wH,
                                                   f16* __restrict__ Qh,
                                                   f16* __restrict__ Kh) {
    __shared__ f16 ot[64 * 264];
    int bid = blockIdx.x;
    int b = bid & 7;
    int r72 = bid >> 3;                 // 0..71
    int z = (r72 >= 36) ? 1 : 0;
    int n0 = (r72 - z * 36) * 64;
    const f16* Wp = wH + (size_t)z * CDIM * CDIM;
    f16* dst = z ? Kh : Qh;
    int tid = threadIdx.x;
    int l = tid & 63, w = tid >> 6;
    int wr = w >> 1, dw = w & 1;
    int lr = l & 15, lg = l >> 4;
    const f16* Xb = Xh + (size_t)b * NPIX * CDIM;

    f32x4 acc[2][8];
#pragma unroll
    for (int rs = 0; rs < 2; ++rs)
#pragma unroll
        for (int dt = 0; dt < 8; ++dt) acc[rs][dt] = {0.f, 0.f, 0.f, 0.f};

#pragma unroll
    for (int ks = 0; ks < 8; ++ks) {
        f16x8 a0 = *(const f16x8*)(Xb + (size_t)(n0 + wr * 32 + lr) * CDIM + ks * 32 + lg * 8);
        f16x8 a1 = *(const f16x8*)(Xb + (size_t)(n0 + wr * 32 + 16 + lr) * CDIM + ks * 32 + lg * 8);
#pragma unroll
        for (int dt = 0; dt < 8; ++dt) {
            f16x8 bf = *(const f16x8*)(Wp + (size_t)(dw * 128 + dt * 16 + lr) * CDIM + ks * 32 + lg * 8);
            acc[0][dt] = MFMA16(a0, bf, acc[0][dt]);
            acc[1][dt] = MFMA16(a1, bf, acc[1][dt]);
        }
    }
#pragma unroll
    for (int rs = 0; rs < 2; ++rs)
#pragma unroll
        for (int dt = 0; dt < 8; ++dt)
#pragma unroll
            for (int reg = 0; reg < 4; ++reg)
                ot[(wr * 32 + rs * 16 + lg * 4 + reg) * 264 + dw * 128 + dt * 16 + lr] =
                    (f16)acc[rs][dt][reg];
    __syncthreads();
#pragma unroll
    for (int rep = 0; rep < 8; ++rep) {
        int flat = rep * 256 + tid;
        int r = flat >> 5, seg = flat & 31;
        *(f16x8*)(dst + (size_t)(b * NPIX + n0 + r) * CDIM + seg * 8) =
            *(const f16x8*)(ot + r * 264 + seg * 8);
    }
}

// ---------------------------------------------------------------------------
// statsAB v3: 64 Q rows/block, 8 waves = (rg row-half 32) x (cw m-slice 16).
// qa pinned in registers (asm), K-fragments register double-buffered so next
// tile's L2 loads overlap current tile's MFMA+exp work.
// 1-D grid 288: b = bid&7 (XCD pinned), n0 = (bid>>3)*64.
// ---------------------------------------------------------------------------
__global__ __launch_bounds__(512, 2) void statsAB_kernel(const f16* __restrict__ Qh,
                                                         const f16* __restrict__ Kh,
                                                         float* __restrict__ invZ,
                                                         float* __restrict__ diagT,
                                                         unsigned* __restrict__ lists,
                                                         int* __restrict__ cnts) {
    __shared__ float zpart[4][64];
    __shared__ float diagbuf[64];
    __shared__ float invZ_s[64];
    __shared__ float thr_s[64];
    __shared__ int cnt_s[64];
    __shared__ unsigned list_s[64][LISTCAP];   // 26.6 KB
    int bid = blockIdx.x;
    int b = bid & 7;
    int n0 = (bid >> 3) * 64;
    int tid = threadIdx.x;
    int l = tid & 63, w = tid >> 6;
    int cw = w & 3, rg = w >> 2;
    int lr = l & 15, lg = l >> 4;
    const f16* Qb = Qh + (size_t)b * NPIX * CDIM;
    const f16* Kb = Kh + (size_t)b * NPIX * CDIM;

    if (tid < 64) cnt_s[tid] = 0;

    f16x8 qa[2][8];
#pragma unroll
    for (int rs = 0; rs < 2; ++rs)
#pragma unroll
        for (int ks = 0; ks < 8; ++ks)
            qa[rs][ks] = *(const f16x8*)(Qb + (size_t)(n0 + rg * 32 + rs * 16 + lr) * CDIM + ks * 32 + lg * 8);
#pragma unroll
    for (int rs = 0; rs < 2; ++rs)
#pragma unroll
        for (int ks = 0; ks < 8; ++ks)
            pinreg(qa[rs][ks]);

    const f16* kbase = Kb + (size_t)(cw * 16 + lr) * CDIM + lg * 8;

    // ---- sweep 1: Z ----
    float zs[2][4] = {{0.f, 0.f, 0.f, 0.f}, {0.f, 0.f, 0.f, 0.f}};
    f16x8 bf[8], bfn[8];
#pragma unroll
    for (int ks = 0; ks < 8; ++ks) bf[ks] = *(const f16x8*)(kbase + ks * 32);
#pragma unroll 1
    for (int mt = 0; mt < 36; ++mt) {
        if (mt < 35) {
            const f16* knext = kbase + (size_t)(mt + 1) * 64 * CDIM;
#pragma unroll
            for (int ks = 0; ks < 8; ++ks) bfn[ks] = *(const f16x8*)(knext + ks * 32);
        }
        f32x4 acc[2] = {{0.f, 0.f, 0.f, 0.f}, {0.f, 0.f, 0.f, 0.f}};
#pragma unroll
        for (int ks = 0; ks < 8; ++ks) {
            acc[0] = MFMA16(qa[0][ks], bf[ks], acc[0]);
            acc[1] = MFMA16(qa[1][ks], bf[ks], acc[1]);
        }
        int m0 = mt * 64;
#pragma unroll
        for (int rs = 0; rs < 2; ++rs)
#pragma unroll
            for (int reg = 0; reg < 4; ++reg) {
                int row64 = rg * 32 + rs * 16 + lg * 4 + reg;
                float e = __expf(acc[rs][reg] - SHIFT);
                zs[rs][reg] += e;
                if (m0 + cw * 16 + lr == n0 + row64) diagbuf[row64] = e;
            }
#pragma unroll
        for (int ks = 0; ks < 8; ++ks) bf[ks] = bfn[ks];
    }
#pragma unroll
    for (int rs = 0; rs < 2; ++rs)
#pragma unroll
        for (int reg = 0; reg < 4; ++reg) {
            float v = zs[rs][reg];
            v += __shfl_xor(v, 1);
            v += __shfl_xor(v, 2);
            v += __shfl_xor(v, 4);
            v += __shfl_xor(v, 8);
            zs[rs][reg] = v;
        }
    if (lr == 0)
#pragma unroll
        for (int rs = 0; rs < 2; ++rs)
#pragma unroll
            for (int reg = 0; reg < 4; ++reg)
                zpart[cw][rg * 32 + rs * 16 + lg * 4 + reg] = zs[rs][reg];
    __syncthreads();
    if (tid < 64) {
        float Z = zpart[0][tid] + zpart[1][tid] + zpart[2][tid] + zpart[3][tid];
        float iz = 1.0f / Z;
        invZ_s[tid] = iz;
        thr_s[tid] = logf(THRESH) - logf(iz) - 1e-3f;   // log(0.01*Z90) - slack
        int n = b * NPIX + n0 + tid;
        invZ[n] = iz;
        float d = diagbuf[tid] * iz;
        diagT[n] = (d < THRESH) ? 0.0f : d;
    }
    __syncthreads();

    float thrv[2][4], izv[2][4];
#pragma unroll
    for (int rs = 0; rs < 2; ++rs)
#pragma unroll
        for (int reg = 0; reg < 4; ++reg) {
            int row64 = rg * 32 + rs * 16 + lg * 4 + reg;
            thrv[rs][reg] = thr_s[row64];
            izv[rs][reg] = invZ_s[row64];
        }

    // ---- sweep 2: filter + append (bitwise-identical L recompute) ----
#pragma unroll
    for (int ks = 0; ks < 8; ++ks) bf[ks] = *(const f16x8*)(kbase + ks * 32);
#pragma unroll 1
    for (int mt = 0; mt < 36; ++mt) {
        if (mt < 35) {
            const f16* knext = kbase + (size_t)(mt + 1) * 64 * CDIM;
#pragma unroll
            for (int ks = 0; ks < 8; ++ks) bfn[ks] = *(const f16x8*)(knext + ks * 32);
        }
        f32x4 acc[2] = {{0.f, 0.f, 0.f, 0.f}, {0.f, 0.f, 0.f, 0.f}};
#pragma unroll
        for (int ks = 0; ks < 8; ++ks) {
            acc[0] = MFMA16(qa[0][ks], bf[ks], acc[0]);
            acc[1] = MFMA16(qa[1][ks], bf[ks], acc[1]);
        }
        int m0 = mt * 64;
#pragma unroll
        for (int rs = 0; rs < 2; ++rs)
#pragma unroll
            for (int reg = 0; reg < 4; ++reg) {
                float lm = acc[rs][reg] - SHIFT;
                if (lm >= thrv[rs][reg]) {
                    float s = __expf(lm) * izv[rs][reg];
                    if (s >= THRESH) {
                        int row64 = rg * 32 + rs * 16 + lg * 4 + reg;
                        int idx = atomicAdd(&cnt_s[row64], 1);
                        if (idx < LISTCAP)
                            list_s[row64][idx] =
                                ((unsigned)(m0 + cw * 16 + lr) << 16) | f16bits((f16)s);
                    }
                }
            }
#pragma unroll
        for (int ks = 0; ks < 8; ++ks) bf[ks] = bfn[ks];
    }
    __syncthreads();
    if (tid < 64) {
        int c = cnt_s[tid];
        cnts[b * NPIX + n0 + tid] = (c > LISTCAP) ? LISTCAP : c;
    }
    unsigned* lblk = lists + (size_t)(b * NPIX + n0) * LISTCAP;
    const unsigned* lsrc = &list_s[0][0];
    for (int i = tid; i < 64 * LISTCAP; i += 512) lblk[i] = lsrc[i];
}

// ---------------------------------------------------------------------------
// sparse (fused with G): nbrH[n][c] = sum_k s_k*Xh[m_k][c] + stencil(Xh)[n][c]
//                                     - diagT[n]*Xh[n][c]
// 1-D grid 576 (b = bid&7 -> XCD pinned); 8 threads/row, 32 cols each, f16x8.
// ---------------------------------------------------------------------------
__global__ __launch_bounds__(256) void sparse_kernel(const unsigned* __restrict__ lists,
                                                     const int* __restrict__ cnts,
                                                     const f16* __restrict__ Xh,
                                                     const float* __restrict__ diagT,
                                                     f16* __restrict__ nbrH) {
    int bid = blockIdx.x;
    int b = bid & 7;
    int n0 = (bid >> 3) * 32;
    int tid = threadIdx.x;
    int r = tid >> 3, t8 = tid & 7;
    int n = n0 + r;
    const f16* Xb = Xh + (size_t)b * NPIX * CDIM;
    int k = cnts[b * NPIX + n];
    const unsigned* lrow = lists + (size_t)(b * NPIX + n) * LISTCAP;

    float accv[32];
#pragma unroll
    for (int j = 0; j < 32; ++j) accv[j] = 0.f;

    auto addrow = [&](int m, float s) {
        const f16* xr = Xb + (size_t)m * CDIM + t8 * 32;
#pragma unroll
        for (int v4 = 0; v4 < 4; ++v4) {
            f16x8 xv = *(const f16x8*)(xr + v4 * 8);
#pragma unroll
            for (int j = 0; j < 8; ++j) accv[v4 * 8 + j] += s * (float)xv[j];
        }
    };

    int hh = n / HWDIM, ww = n % HWDIM;
    if (hh > 0)         addrow(n - HWDIM, 1.0f);
    if (hh < HWDIM - 1) addrow(n + HWDIM, 1.0f);
    if (ww > 0)         addrow(n - 1, 1.0f);
    if (ww < HWDIM - 1) addrow(n + 1, 1.0f);
    addrow(n, -diagT[b * NPIX + n]);

    for (int i = 0; i < k; ++i) {
        unsigned pk = lrow[i];
        addrow((int)(pk >> 16), (float)bits2f16((unsigned short)(pk & 0xffffu)));
    }

    f16* orow = nbrH + ((size_t)b * NPIX + n) * CDIM + t8 * 32;
#pragma unroll
    for (int v4 = 0; v4 < 4; ++v4) {
        f16x8 ov;
#pragma unroll
        for (int j = 0; j < 8; ++j) ov[j] = (f16)accv[v4 * 8 + j];
        *(f16x8*)(orow + v4 * 8) = ov;
    }
}

// ---------------------------------------------------------------------------
// final: out[b][d][n] = relu( (1+diagT[n])·(Xh·w0ᵀ)[n][d] + (nbrH·w1ᵀ)[n][d] )
// 1-D grid 288 (b = bid&7 -> XCD pinned).
// ---------------------------------------------------------------------------
__global__ __launch_bounds__(256) void final_kernel(const f16* __restrict__ Xh,
                                                    const f16* __restrict__ nbrH,
                                                    const f16* __restrict__ wH,
                                                    const float* __restrict__ diagT,
                                                    float* __restrict__ out) {
    int bid = blockIdx.x;
    int b = bid & 7;
    int n0 = (bid >> 3) * 64;
    int tid = threadIdx.x;
    int l = tid & 63, w = tid >> 6;
    int wr = w >> 1, dw = w & 1;
    int lr = l & 15, lg = l >> 4;
    const f16* Xb = Xh + (size_t)b * NPIX * CDIM;
    const f16* Nb = nbrH + (size_t)b * NPIX * CDIM;
    const f16* w0H = wH + 2 * CDIM * CDIM;
    const f16* w1H = wH + 3 * CDIM * CDIM;

    f32x4 acc[2][8];
#pragma unroll
    for (int rs = 0; rs < 2; ++rs)
#pragma unroll
        for (int dt = 0; dt < 8; ++dt) acc[rs][dt] = {0.f, 0.f, 0.f, 0.f};

#pragma unroll
    for (int ks = 0; ks < 8; ++ks) {
        f16x8 a0 = *(const f16x8*)(Xb + (size_t)(n0 + wr * 32 + lr) * CDIM + ks * 32 + lg * 8);
        f16x8 a1 = *(const f16x8*)(Xb + (size_t)(n0 + wr * 32 + 16 + lr) * CDIM + ks * 32 + lg * 8);
#pragma unroll
        for (int dt = 0; dt < 8; ++dt) {
            f16x8 bf = *(const f16x8*)(w0H + (size_t)(dw * 128 + dt * 16 + lr) * CDIM + ks * 32 + lg * 8);
            acc[0][dt] = MFMA16(a0, bf, acc[0][dt]);
            acc[1][dt] = MFMA16(a1, bf, acc[1][dt]);
        }
    }
#pragma unroll
    for (int rs = 0; rs < 2; ++rs)
#pragma unroll
        for (int reg = 0; reg < 4; ++reg) {
            int n = n0 + wr * 32 + rs * 16 + lg * 4 + reg;
            float s = 1.0f + diagT[b * NPIX + n];
#pragma unroll
            for (int dt = 0; dt < 8; ++dt) acc[rs][dt][reg] *= s;
        }
#pragma unroll
    for (int ks = 0; ks < 8; ++ks) {
        f16x8 a0 = *(const f16x8*)(Nb + (size_t)(n0 + wr * 32 + lr) * CDIM + ks * 32 + lg * 8);
        f16x8 a1 = *(const f16x8*)(Nb + (size_t)(n0 + wr * 32 + 16 + lr) * CDIM + ks * 32 + lg * 8);
#pragma unroll
        for (int dt = 0; dt < 8; ++dt) {
            f16x8 bf = *(const f16x8*)(w1H + (size_t)(dw * 128 + dt * 16 + lr) * CDIM + ks * 32 + lg * 8);
            acc[0][dt] = MFMA16(a0, bf, acc[0][dt]);
            acc[1][dt] = MFMA16(a1, bf, acc[1][dt]);
        }
    }
#pragma unroll
    for (int rs = 0; rs < 2; ++rs)
#pragma unroll
        for (int dt = 0; dt < 8; ++dt) {
            int d = dw * 128 + dt * 16 + lr;
            int nb_ = n0 + wr * 32 + rs * 16 + lg * 4;
            f32x4 v = acc[rs][dt];
#pragma unroll
            for (int reg = 0; reg < 4; ++reg) v[reg] = fmaxf(v[reg], 0.0f);
            *(f32x4*)(out + ((size_t)b * CDIM + d) * NPIX + nb_) = v;
        }
}

extern "C" void kernel_launch(void* const* d_in, const int* in_sizes, int n_in,
                              void* d_out, int out_size, void* d_ws, size_t ws_size,
                              hipStream_t stream) {
    const float* x   = (const float*)d_in[0];
    const float* phi = (const float*)d_in[1];
    const float* psi = (const float*)d_in[2];
    const float* w0  = (const float*)d_in[3];
    const float* w1  = (const float*)d_in[4];
    float* out = (float*)d_out;

    const size_t BNC = (size_t)BATCH * NPIX * CDIM;
    const size_t BN  = (size_t)BATCH * NPIX;
    char* p = (char*)d_ws;
    auto alloc = [&](size_t bytes) { char* r = p; p += (bytes + 255) & ~(size_t)255; return r; };
    f16*      Xh    = (f16*)alloc(BNC * 2);
    f16*      Qh    = (f16*)alloc(BNC * 2);
    f16*      Kh    = (f16*)alloc(BNC * 2);
    f16*      nbrH  = (f16*)alloc(BNC * 2);
    f16*      wH    = (f16*)alloc((size_t)4 * CDIM * CDIM * 2);
    float*    invZ  = (float*)alloc(BN * 4);
    float*    diagT = (float*)alloc(BN * 4);
    unsigned* lists = (unsigned*)alloc(BN * LISTCAP * 4);   // 7.7 MB
    int*      cnts  = (int*)alloc(BN * 4);

    prep_kernel<<<dim3(72, 8, 9), 256, 0, stream>>>(x, phi, psi, w0, w1, Xh, wH);
    proj_kernel<<<dim3(576), 256, 0, stream>>>(Xh, wH, Qh, Kh);
    statsAB_kernel<<<dim3(288), 512, 0, stream>>>(Qh, Kh, invZ, diagT, lists, cnts);
    sparse_kernel<<<dim3(576), 256, 0, stream>>>(lists, cnts, Xh, diagT, nbrH);
    final_kernel<<<dim3(288), 256, 0, stream>>>(Xh, nbrH, wH, diagT, out);
}

// Round 11
// 337.628 us; speedup vs baseline: 1.2596x; 1.2596x over previous
//
#include <hip/hip_runtime.h>

#define HWDIM 48
#define NPIX 2304   // 48*48
#define CDIM 256
#define BATCH 8
#define THRESH 0.01f
#define SHIFT 90.0f
#define LISTCAP 104   // ≥ max survivors per row (≤100 since sum(S)=1, S>=0.01)
#define MCHUNK 576    // NPIX/4 m-rows per chunk, 9 tiles of 64

typedef _Float16 f16;
typedef _Float16 f16x8 __attribute__((ext_vector_type(8)));
typedef float f32x4 __attribute__((ext_vector_type(4)));

#define MFMA16(a, b, c) __builtin_amdgcn_mfma_f32_16x16x32_f16(a, b, c, 0, 0, 0)

static __device__ __forceinline__ unsigned short f16bits(f16 v) {
    return __builtin_bit_cast(unsigned short, v);
}
static __device__ __forceinline__ f16 bits2f16(unsigned short u) {
    return __builtin_bit_cast(f16, u);
}

// ---------------------------------------------------------------------------
// prep: Xh[b][n][c] = (f16)x[b][c][n]; wH = f16 casts of weights; zero Z/cnts.
// grid (72, 8, 9) block 256; z==8 handles weights + zeroing.
// ---------------------------------------------------------------------------
__global__ __launch_bounds__(256) void prep_kernel(const float* __restrict__ x,
                                                   const float* __restrict__ phi,
                                                   const float* __restrict__ psi,
                                                   const float* __restrict__ w0,
                                                   const float* __restrict__ w1,
                                                   f16* __restrict__ Xh,
                                                   f16* __restrict__ wH,
                                                   float* __restrict__ Zbuf,
                                                   int* __restrict__ cnts) {
    if (blockIdx.z == BATCH) {
        int bid = blockIdx.y * gridDim.x + blockIdx.x;
        int t = bid * 256 + threadIdx.x;                 // 0..147455
        for (int i = t; i < 4 * CDIM * CDIM; i += 576 * 256) {
            const float* src = (i < 65536) ? phi : (i < 131072) ? psi
                               : (i < 196608) ? w0 : w1;
            wH[i] = (f16)src[i & 65535];
        }
        for (int i = t; i < BATCH * NPIX; i += 576 * 256) {
            Zbuf[i] = 0.0f;
            cnts[i] = 0;
        }
        return;
    }
    __shared__ float tile[32][33];
    int b = blockIdx.z;
    int n0 = blockIdx.x * 32, c0 = blockIdx.y * 32;
    int tx = threadIdx.x & 31, ty = threadIdx.x >> 5;
    const float* xb = x + (size_t)b * CDIM * NPIX;
    f16* XhB = Xh + (size_t)b * NPIX * CDIM;
#pragma unroll
    for (int j = 0; j < 4; ++j) {
        int c = c0 + ty + 8 * j;
        tile[ty + 8 * j][tx] = xb[(size_t)c * NPIX + n0 + tx];
    }
    __syncthreads();
#pragma unroll
    for (int j = 0; j < 4; ++j) {
        int n = n0 + ty + 8 * j;
        XhB[(size_t)n * CDIM + c0 + tx] = (f16)tile[tx][ty + 8 * j];
    }
}

// ---------------------------------------------------------------------------
// proj: Qh = Xh·phiᵀ / Kh = Xh·psiᵀ. 1-D grid 576 (b = bid&7 -> XCD pinned).
// ---------------------------------------------------------------------------
__global__ __launch_bounds__(256) void proj_kernel(const f16* __restrict__ Xh,
                                                   const f16* __restrict__ wH,
                                                   f16* __restrict__ Qh,
                                                   f16* __restrict__ Kh) {
    __shared__ f16 ot[64 * 264];
    int bid = blockIdx.x;
    int b = bid & 7;
    int r72 = bid >> 3;                 // 0..71
    int z = (r72 >= 36) ? 1 : 0;
    int n0 = (r72 - z * 36) * 64;
    const f16* Wp = wH + (size_t)z * CDIM * CDIM;
    f16* dst = z ? Kh : Qh;
    int tid = threadIdx.x;
    int l = tid & 63, w = tid >> 6;
    int wr = w >> 1, dw = w & 1;
    int lr = l & 15, lg = l >> 4;
    const f16* Xb = Xh + (size_t)b * NPIX * CDIM;

    f32x4 acc[2][8];
#pragma unroll
    for (int rs = 0; rs < 2; ++rs)
#pragma unroll
        for (int dt = 0; dt < 8; ++dt) acc[rs][dt] = {0.f, 0.f, 0.f, 0.f};

#pragma unroll
    for (int ks = 0; ks < 8; ++ks) {
        f16x8 a0 = *(const f16x8*)(Xb + (size_t)(n0 + wr * 32 + lr) * CDIM + ks * 32 + lg * 8);
        f16x8 a1 = *(const f16x8*)(Xb + (size_t)(n0 + wr * 32 + 16 + lr) * CDIM + ks * 32 + lg * 8);
#pragma unroll
        for (int dt = 0; dt < 8; ++dt) {
            f16x8 bf = *(const f16x8*)(Wp + (size_t)(dw * 128 + dt * 16 + lr) * CDIM + ks * 32 + lg * 8);
            acc[0][dt] = MFMA16(a0, bf, acc[0][dt]);
            acc[1][dt] = MFMA16(a1, bf, acc[1][dt]);
        }
    }
#pragma unroll
    for (int rs = 0; rs < 2; ++rs)
#pragma unroll
        for (int dt = 0; dt < 8; ++dt)
#pragma unroll
            for (int reg = 0; reg < 4; ++reg)
                ot[(wr * 32 + rs * 16 + lg * 4 + reg) * 264 + dw * 128 + dt * 16 + lr] =
                    (f16)acc[rs][dt][reg];
    __syncthreads();
#pragma unroll
    for (int rep = 0; rep < 8; ++rep) {
        int flat = rep * 256 + tid;
        int r = flat >> 5, seg = flat & 31;
        *(f16x8*)(dst + (size_t)(b * NPIX + n0 + r) * CDIM + seg * 8) =
            *(const f16x8*)(ot + r * 264 + seg * 8);
    }
}

// ---------------------------------------------------------------------------
// zpass: partial Z over one m-chunk (576 m-rows = 9 tiles), Q staged in LDS.
// grid 2304: b = bid&7 (XCD pinned), r = bid>>3: n0 = (r>>2)*32, mc = r&3.
// Block partial Z -> one atomicAdd per row. Diag e written (unique writer).
// ---------------------------------------------------------------------------
__global__ __launch_bounds__(256) void zpass_kernel(const f16* __restrict__ Qh,
                                                    const f16* __restrict__ Kh,
                                                    float* __restrict__ Zbuf,
                                                    float* __restrict__ ediag) {
    __shared__ f16 Qs[32 * 264];
    __shared__ float zpart[4][32];
    int bid = blockIdx.x;
    int b = bid & 7;
    int r = bid >> 3;
    int n0 = (r >> 2) * 32;
    int mc = r & 3;
    int tid = threadIdx.x;
    int l = tid & 63, cw = tid >> 6;
    int lr = l & 15, lg = l >> 4;
    const f16* Qb = Qh + (size_t)b * NPIX * CDIM;
    const f16* Kb = Kh + (size_t)b * NPIX * CDIM;

#pragma unroll
    for (int rep = 0; rep < 4; ++rep) {
        int idx = rep * 256 + tid;           // 1024 chunks of 8 f16
        int row = idx >> 5, seg = idx & 31;
        *(f16x8*)(Qs + row * 264 + seg * 8) =
            *(const f16x8*)(Qb + (size_t)(n0 + row) * CDIM + seg * 8);
    }
    __syncthreads();

    const f16* kbase = Kb + (size_t)(mc * MCHUNK + cw * 16 + lr) * CDIM + lg * 8;
    float zs[2][4] = {{0.f, 0.f, 0.f, 0.f}, {0.f, 0.f, 0.f, 0.f}};
#pragma unroll 1
    for (int mt = 0; mt < 9; ++mt) {
        const f16* kp = kbase + (size_t)mt * 64 * CDIM;
        f32x4 acc[2] = {{0.f, 0.f, 0.f, 0.f}, {0.f, 0.f, 0.f, 0.f}};
#pragma unroll
        for (int ks = 0; ks < 8; ++ks) {
            f16x8 bf = *(const f16x8*)(kp + ks * 32);
            f16x8 qa0 = *(const f16x8*)(Qs + lr * 264 + ks * 32 + lg * 8);
            f16x8 qa1 = *(const f16x8*)(Qs + (16 + lr) * 264 + ks * 32 + lg * 8);
            acc[0] = MFMA16(qa0, bf, acc[0]);
            acc[1] = MFMA16(qa1, bf, acc[1]);
        }
        int m0 = mc * MCHUNK + mt * 64;
#pragma unroll
        for (int rs = 0; rs < 2; ++rs)
#pragma unroll
            for (int reg = 0; reg < 4; ++reg) {
                int row32 = rs * 16 + lg * 4 + reg;
                float e = __expf(acc[rs][reg] - SHIFT);
                zs[rs][reg] += e;
                if (m0 + cw * 16 + lr == n0 + row32)
                    ediag[b * NPIX + n0 + row32] = e;
            }
    }
#pragma unroll
    for (int rs = 0; rs < 2; ++rs)
#pragma unroll
        for (int reg = 0; reg < 4; ++reg) {
            float v = zs[rs][reg];
            v += __shfl_xor(v, 1);
            v += __shfl_xor(v, 2);
            v += __shfl_xor(v, 4);
            v += __shfl_xor(v, 8);
            zs[rs][reg] = v;
        }
    if (lr == 0)
#pragma unroll
        for (int rs = 0; rs < 2; ++rs)
#pragma unroll
            for (int reg = 0; reg < 4; ++reg)
                zpart[cw][rs * 16 + lg * 4 + reg] = zs[rs][reg];
    __syncthreads();
    if (tid < 32) {
        float Zp = zpart[0][tid] + zpart[1][tid] + zpart[2][tid] + zpart[3][tid];
        atomicAdd(&Zbuf[b * NPIX + n0 + tid], Zp);
    }
}

// ---------------------------------------------------------------------------
// filter: recompute L over the same m-chunk (bitwise-identical MFMA chain),
// threshold s = exp(L-90)/Z, append packed (m<<16|f16(s)) via global atomics.
// mc==0 blocks also produce diagT (consistent: same iz, same e as zpass).
// ---------------------------------------------------------------------------
__global__ __launch_bounds__(256) void filter_kernel(const f16* __restrict__ Qh,
                                                     const f16* __restrict__ Kh,
                                                     const float* __restrict__ Zbuf,
                                                     const float* __restrict__ ediag,
                                                     float* __restrict__ diagT,
                                                     unsigned* __restrict__ lists,
                                                     int* __restrict__ cnts) {
    __shared__ f16 Qs[32 * 264];
    __shared__ float invZ_s[32];
    __shared__ float thr_s[32];
    int bid = blockIdx.x;
    int b = bid & 7;
    int r = bid >> 3;
    int n0 = (r >> 2) * 32;
    int mc = r & 3;
    int tid = threadIdx.x;
    int l = tid & 63, cw = tid >> 6;
    int lr = l & 15, lg = l >> 4;
    const f16* Qb = Qh + (size_t)b * NPIX * CDIM;
    const f16* Kb = Kh + (size_t)b * NPIX * CDIM;

#pragma unroll
    for (int rep = 0; rep < 4; ++rep) {
        int idx = rep * 256 + tid;
        int row = idx >> 5, seg = idx & 31;
        *(f16x8*)(Qs + row * 264 + seg * 8) =
            *(const f16x8*)(Qb + (size_t)(n0 + row) * CDIM + seg * 8);
    }
    if (tid < 32) {
        int n = b * NPIX + n0 + tid;
        float Z = Zbuf[n];
        float iz = 1.0f / Z;
        invZ_s[tid] = iz;
        thr_s[tid] = logf(THRESH) + logf(Z) - 1e-3f;   // log(0.01*Z) - slack
        if (mc == 0) {
            float d = ediag[n] * iz;
            diagT[n] = (d < THRESH) ? 0.0f : d;
        }
    }
    __syncthreads();

    float thrv[2][4], izv[2][4];
#pragma unroll
    for (int rs = 0; rs < 2; ++rs)
#pragma unroll
        for (int reg = 0; reg < 4; ++reg) {
            int row32 = rs * 16 + lg * 4 + reg;
            thrv[rs][reg] = thr_s[row32];
            izv[rs][reg] = invZ_s[row32];
        }

    const f16* kbase = Kb + (size_t)(mc * MCHUNK + cw * 16 + lr) * CDIM + lg * 8;
#pragma unroll 1
    for (int mt = 0; mt < 9; ++mt) {
        const f16* kp = kbase + (size_t)mt * 64 * CDIM;
        f32x4 acc[2] = {{0.f, 0.f, 0.f, 0.f}, {0.f, 0.f, 0.f, 0.f}};
#pragma unroll
        for (int ks = 0; ks < 8; ++ks) {
            f16x8 bf = *(const f16x8*)(kp + ks * 32);
            f16x8 qa0 = *(const f16x8*)(Qs + lr * 264 + ks * 32 + lg * 8);
            f16x8 qa1 = *(const f16x8*)(Qs + (16 + lr) * 264 + ks * 32 + lg * 8);
            acc[0] = MFMA16(qa0, bf, acc[0]);
            acc[1] = MFMA16(qa1, bf, acc[1]);
        }
        int m0 = mc * MCHUNK + mt * 64;
#pragma unroll
        for (int rs = 0; rs < 2; ++rs)
#pragma unroll
            for (int reg = 0; reg < 4; ++reg) {
                float lm = acc[rs][reg] - SHIFT;
                if (lm >= thrv[rs][reg]) {
                    float s = __expf(lm) * izv[rs][reg];
                    if (s >= THRESH) {
                        int row32 = rs * 16 + lg * 4 + reg;
                        int n = b * NPIX + n0 + row32;
                        int idx = atomicAdd(&cnts[n], 1);
                        if (idx < LISTCAP)
                            lists[(size_t)n * LISTCAP + idx] =
                                ((unsigned)(m0 + cw * 16 + lr) << 16) | f16bits((f16)s);
                    }
                }
            }
    }
}

// ---------------------------------------------------------------------------
// sparse (fused stencil): nbrH[n][c] = sum_k s_k*Xh[m_k][c] + stencil(Xh)[n][c]
//                                       - diagT[n]*Xh[n][c]
// 1-D grid 576 (b = bid&7 -> XCD pinned); 8 threads/row, 32 cols each, f16x8.
// ---------------------------------------------------------------------------
__global__ __launch_bounds__(256) void sparse_kernel(const unsigned* __restrict__ lists,
                                                     const int* __restrict__ cnts,
                                                     const f16* __restrict__ Xh,
                                                     const float* __restrict__ diagT,
                                                     f16* __restrict__ nbrH) {
    int bid = blockIdx.x;
    int b = bid & 7;
    int n0 = (bid >> 3) * 32;
    int tid = threadIdx.x;
    int r = tid >> 3, t8 = tid & 7;
    int n = n0 + r;
    const f16* Xb = Xh + (size_t)b * NPIX * CDIM;
    int k = cnts[b * NPIX + n];
    if (k > LISTCAP) k = LISTCAP;
    const unsigned* lrow = lists + (size_t)(b * NPIX + n) * LISTCAP;

    float accv[32];
#pragma unroll
    for (int j = 0; j < 32; ++j) accv[j] = 0.f;

    auto addrow = [&](int m, float s) {
        const f16* xr = Xb + (size_t)m * CDIM + t8 * 32;
#pragma unroll
        for (int v4 = 0; v4 < 4; ++v4) {
            f16x8 xv = *(const f16x8*)(xr + v4 * 8);
#pragma unroll
            for (int j = 0; j < 8; ++j) accv[v4 * 8 + j] += s * (float)xv[j];
        }
    };

    int hh = n / HWDIM, ww = n % HWDIM;
    if (hh > 0)         addrow(n - HWDIM, 1.0f);
    if (hh < HWDIM - 1) addrow(n + HWDIM, 1.0f);
    if (ww > 0)         addrow(n - 1, 1.0f);
    if (ww < HWDIM - 1) addrow(n + 1, 1.0f);
    addrow(n, -diagT[b * NPIX + n]);

    for (int i = 0; i < k; ++i) {
        unsigned pk = lrow[i];
        addrow((int)(pk >> 16), (float)bits2f16((unsigned short)(pk & 0xffffu)));
    }

    f16* orow = nbrH + ((size_t)b * NPIX + n) * CDIM + t8 * 32;
#pragma unroll
    for (int v4 = 0; v4 < 4; ++v4) {
        f16x8 ov;
#pragma unroll
        for (int j = 0; j < 8; ++j) ov[j] = (f16)accv[v4 * 8 + j];
        *(f16x8*)(orow + v4 * 8) = ov;
    }
}

// ---------------------------------------------------------------------------
// final: out[b][d][n] = relu( (1+diagT[n])·(Xh·w0ᵀ)[n][d] + (nbrH·w1ᵀ)[n][d] )
// 1-D grid 288 (b = bid&7 -> XCD pinned).
// ---------------------------------------------------------------------------
__global__ __launch_bounds__(256) void final_kernel(const f16* __restrict__ Xh,
                                                    const f16* __restrict__ nbrH,
                                                    const f16* __restrict__ wH,
                                                    const float* __restrict__ diagT,
                                                    float* __restrict__ out) {
    int bid = blockIdx.x;
    int b = bid & 7;
    int n0 = (bid >> 3) * 64;
    int tid = threadIdx.x;
    int l = tid & 63, w = tid >> 6;
    int wr = w >> 1, dw = w & 1;
    int lr = l & 15, lg = l >> 4;
    const f16* Xb = Xh + (size_t)b * NPIX * CDIM;
    const f16* Nb = nbrH + (size_t)b * NPIX * CDIM;
    const f16* w0H = wH + 2 * CDIM * CDIM;
    const f16* w1H = wH + 3 * CDIM * CDIM;

    f32x4 acc[2][8];
#pragma unroll
    for (int rs = 0; rs < 2; ++rs)
#pragma unroll
        for (int dt = 0; dt < 8; ++dt) acc[rs][dt] = {0.f, 0.f, 0.f, 0.f};

#pragma unroll
    for (int ks = 0; ks < 8; ++ks) {
        f16x8 a0 = *(const f16x8*)(Xb + (size_t)(n0 + wr * 32 + lr) * CDIM + ks * 32 + lg * 8);
        f16x8 a1 = *(const f16x8*)(Xb + (size_t)(n0 + wr * 32 + 16 + lr) * CDIM + ks * 32 + lg * 8);
#pragma unroll
        for (int dt = 0; dt < 8; ++dt) {
            f16x8 bf = *(const f16x8*)(w0H + (size_t)(dw * 128 + dt * 16 + lr) * CDIM + ks * 32 + lg * 8);
            acc[0][dt] = MFMA16(a0, bf, acc[0][dt]);
            acc[1][dt] = MFMA16(a1, bf, acc[1][dt]);
        }
    }
#pragma unroll
    for (int rs = 0; rs < 2; ++rs)
#pragma unroll
        for (int reg = 0; reg < 4; ++reg) {
            int n = n0 + wr * 32 + rs * 16 + lg * 4 + reg;
            float s = 1.0f + diagT[b * NPIX + n];
#pragma unroll
            for (int dt = 0; dt < 8; ++dt) acc[rs][dt][reg] *= s;
        }
#pragma unroll
    for (int ks = 0; ks < 8; ++ks) {
        f16x8 a0 = *(const f16x8*)(Nb + (size_t)(n0 + wr * 32 + lr) * CDIM + ks * 32 + lg * 8);
        f16x8 a1 = *(const f16x8*)(Nb + (size_t)(n0 + wr * 32 + 16 + lr) * CDIM + ks * 32 + lg * 8);
#pragma unroll
        for (int dt = 0; dt < 8; ++dt) {
            f16x8 bf = *(const f16x8*)(w1H + (size_t)(dw * 128 + dt * 16 + lr) * CDIM + ks * 32 + lg * 8);
            acc[0][dt] = MFMA16(a0, bf, acc[0][dt]);
            acc[1][dt] = MFMA16(a1, bf, acc[1][dt]);
        }
    }
#pragma unroll
    for (int rs = 0; rs < 2; ++rs)
#pragma unroll
        for (int dt = 0; dt < 8; ++dt) {
            int d = dw * 128 + dt * 16 + lr;
            int nb_ = n0 + wr * 32 + rs * 16 + lg * 4;
            f32x4 v = acc[rs][dt];
#pragma unroll
            for (int reg = 0; reg < 4; ++reg) v[reg] = fmaxf(v[reg], 0.0f);
            *(f32x4*)(out + ((size_t)b * CDIM + d) * NPIX + nb_) = v;
        }
}

extern "C" void kernel_launch(void* const* d_in, const int* in_sizes, int n_in,
                              void* d_out, int out_size, void* d_ws, size_t ws_size,
                              hipStream_t stream) {
    const float* x   = (const float*)d_in[0];
    const float* phi = (const float*)d_in[1];
    const float* psi = (const float*)d_in[2];
    const float* w0  = (const float*)d_in[3];
    const float* w1  = (const float*)d_in[4];
    float* out = (float*)d_out;

    const size_t BNC = (size_t)BATCH * NPIX * CDIM;
    const size_t BN  = (size_t)BATCH * NPIX;
    char* p = (char*)d_ws;
    auto alloc = [&](size_t bytes) { char* r = p; p += (bytes + 255) & ~(size_t)255; return r; };
    f16*      Xh    = (f16*)alloc(BNC * 2);
    f16*      Qh    = (f16*)alloc(BNC * 2);
    f16*      Kh    = (f16*)alloc(BNC * 2);
    f16*      nbrH  = (f16*)alloc(BNC * 2);
    f16*      wH    = (f16*)alloc((size_t)4 * CDIM * CDIM * 2);
    float*    Zbuf  = (float*)alloc(BN * 4);
    float*    ediag = (float*)alloc(BN * 4);
    float*    diagT = (float*)alloc(BN * 4);
    unsigned* lists = (unsigned*)alloc(BN * LISTCAP * 4);   // 7.7 MB
    int*      cnts  = (int*)alloc(BN * 4);

    prep_kernel<<<dim3(72, 8, 9), 256, 0, stream>>>(x, phi, psi, w0, w1, Xh, wH, Zbuf, cnts);
    proj_kernel<<<dim3(576), 256, 0, stream>>>(Xh, wH, Qh, Kh);
    zpass_kernel<<<dim3(2304), 256, 0, stream>>>(Qh, Kh, Zbuf, ediag);
    filter_kernel<<<dim3(2304), 256, 0, stream>>>(Qh, Kh, Zbuf, ediag, diagT, lists, cnts);
    sparse_kernel<<<dim3(576), 256, 0, stream>>>(lists, cnts, Xh, diagT, nbrH);
    final_kernel<<<dim3(288), 256, 0, stream>>>(Xh, nbrH, wH, diagT, out);
}

// Round 12
// 324.191 us; speedup vs baseline: 1.3118x; 1.0414x over previous
//
#include <hip/hip_runtime.h>

#define HWDIM 48
#define NPIX 2304   // 48*48
#define CDIM 256
#define BATCH 8
#define THRESH 0.01f
#define SHIFT 90.0f
#define LISTCAP 104   // ≥ max survivors per row (≤100 since sum(S)=1, S>=0.01)

typedef _Float16 f16;
typedef _Float16 f16x8 __attribute__((ext_vector_type(8)));
typedef float f32x4 __attribute__((ext_vector_type(4)));

#define MFMA16(a, b, c) __builtin_amdgcn_mfma_f32_16x16x32_f16(a, b, c, 0, 0, 0)

static __device__ __forceinline__ unsigned short f16bits(f16 v) {
    return __builtin_bit_cast(unsigned short, v);
}
static __device__ __forceinline__ f16 bits2f16(unsigned short u) {
    return __builtin_bit_cast(f16, u);
}

// ---------------------------------------------------------------------------
// prep: Xh[b][n][c] = (f16)x[b][c][n]; wH = f16 casts of weights; zero Z/cnts.
// grid (72, 8, 9) block 256; z==8 handles weights + zeroing.
// ---------------------------------------------------------------------------
__global__ __launch_bounds__(256) void prep_kernel(const float* __restrict__ x,
                                                   const float* __restrict__ phi,
                                                   const float* __restrict__ psi,
                                                   const float* __restrict__ w0,
                                                   const float* __restrict__ w1,
                                                   f16* __restrict__ Xh,
                                                   f16* __restrict__ wH,
                                                   float* __restrict__ Zbuf,
                                                   int* __restrict__ cnts) {
    if (blockIdx.z == BATCH) {
        int bid = blockIdx.y * gridDim.x + blockIdx.x;
        int t = bid * 256 + threadIdx.x;                 // 0..147455
        for (int i = t; i < 4 * CDIM * CDIM; i += 576 * 256) {
            const float* src = (i < 65536) ? phi : (i < 131072) ? psi
                               : (i < 196608) ? w0 : w1;
            wH[i] = (f16)src[i & 65535];
        }
        for (int i = t; i < BATCH * NPIX; i += 576 * 256) {
            Zbuf[i] = 0.0f;
            cnts[i] = 0;
        }
        return;
    }
    __shared__ float tile[32][33];
    int b = blockIdx.z;
    int n0 = blockIdx.x * 32, c0 = blockIdx.y * 32;
    int tx = threadIdx.x & 31, ty = threadIdx.x >> 5;
    const float* xb = x + (size_t)b * CDIM * NPIX;
    f16* XhB = Xh + (size_t)b * NPIX * CDIM;
#pragma unroll
    for (int j = 0; j < 4; ++j) {
        int c = c0 + ty + 8 * j;
        tile[ty + 8 * j][tx] = xb[(size_t)c * NPIX + n0 + tx];
    }
    __syncthreads();
#pragma unroll
    for (int j = 0; j < 4; ++j) {
        int n = n0 + ty + 8 * j;
        XhB[(size_t)n * CDIM + c0 + tx] = (f16)tile[tx][ty + 8 * j];
    }
}

// ---------------------------------------------------------------------------
// proj: Qh = Xh·phiᵀ / Kh = Xh·psiᵀ. 1-D grid 576 (b = bid&7 -> XCD pinned).
// ---------------------------------------------------------------------------
__global__ __launch_bounds__(256) void proj_kernel(const f16* __restrict__ Xh,
                                                   const f16* __restrict__ wH,
                                                   f16* __restrict__ Qh,
                                                   f16* __restrict__ Kh) {
    __shared__ f16 ot[64 * 264];
    int bid = blockIdx.x;
    int b = bid & 7;
    int r72 = bid >> 3;                 // 0..71
    int z = (r72 >= 36) ? 1 : 0;
    int n0 = (r72 - z * 36) * 64;
    const f16* Wp = wH + (size_t)z * CDIM * CDIM;
    f16* dst = z ? Kh : Qh;
    int tid = threadIdx.x;
    int l = tid & 63, w = tid >> 6;
    int wr = w >> 1, dw = w & 1;
    int lr = l & 15, lg = l >> 4;
    const f16* Xb = Xh + (size_t)b * NPIX * CDIM;

    f32x4 acc[2][8];
#pragma unroll
    for (int rs = 0; rs < 2; ++rs)
#pragma unroll
        for (int dt = 0; dt < 8; ++dt) acc[rs][dt] = {0.f, 0.f, 0.f, 0.f};

#pragma unroll
    for (int ks = 0; ks < 8; ++ks) {
        f16x8 a0 = *(const f16x8*)(Xb + (size_t)(n0 + wr * 32 + lr) * CDIM + ks * 32 + lg * 8);
        f16x8 a1 = *(const f16x8*)(Xb + (size_t)(n0 + wr * 32 + 16 + lr) * CDIM + ks * 32 + lg * 8);
#pragma unroll
        for (int dt = 0; dt < 8; ++dt) {
            f16x8 bf = *(const f16x8*)(Wp + (size_t)(dw * 128 + dt * 16 + lr) * CDIM + ks * 32 + lg * 8);
            acc[0][dt] = MFMA16(a0, bf, acc[0][dt]);
            acc[1][dt] = MFMA16(a1, bf, acc[1][dt]);
        }
    }
#pragma unroll
    for (int rs = 0; rs < 2; ++rs)
#pragma unroll
        for (int dt = 0; dt < 8; ++dt)
#pragma unroll
            for (int reg = 0; reg < 4; ++reg)
                ot[(wr * 32 + rs * 16 + lg * 4 + reg) * 264 + dw * 128 + dt * 16 + lr] =
                    (f16)acc[rs][dt][reg];
    __syncthreads();
#pragma unroll
    for (int rep = 0; rep < 8; ++rep) {
        int flat = rep * 256 + tid;
        int r = flat >> 5, seg = flat & 31;
        *(f16x8*)(dst + (size_t)(b * NPIX + n0 + r) * CDIM + seg * 8) =
            *(const f16x8*)(ot + r * 264 + seg * 8);
    }
}

// ---------------------------------------------------------------------------
// zpass v3: 8 independent MFMA chains per wave (2 row-frags x 4 col-frags).
// Each wave owns one full 64-col m-tile; block's 4 waves = 4 consecutive tiles.
// grid 5184: b = bid&7 (XCD pinned); r = bid>>3: mc = r/72 (chunk of 4 tiles),
// n0 = (r%72)*32. Partial Z -> one atomicAdd per row per block.
// ---------------------------------------------------------------------------
__global__ __launch_bounds__(256) void zpass_kernel(const f16* __restrict__ Qh,
                                                    const f16* __restrict__ Kh,
                                                    float* __restrict__ Zbuf,
                                                    float* __restrict__ ediag) {
    __shared__ f16 Qs[32 * 264];
    __shared__ float zpart[4][32];
    int bid = blockIdx.x;
    int b = bid & 7;
    int r = bid >> 3;
    int mc = r / 72;
    int n0 = (r % 72) * 32;
    int tid = threadIdx.x;
    int l = tid & 63, w = tid >> 6;
    int lr = l & 15, lg = l >> 4;
    const f16* Qb = Qh + (size_t)b * NPIX * CDIM;
    const f16* Kb = Kh + (size_t)b * NPIX * CDIM;

#pragma unroll
    for (int rep = 0; rep < 4; ++rep) {
        int idx = rep * 256 + tid;           // 1024 chunks of 8 f16
        int row = idx >> 5, seg = idx & 31;
        *(f16x8*)(Qs + row * 264 + seg * 8) =
            *(const f16x8*)(Qb + (size_t)(n0 + row) * CDIM + seg * 8);
    }
    __syncthreads();

    int m0 = (mc * 4 + w) * 64;
    f32x4 acc[2][4];
#pragma unroll
    for (int rs = 0; rs < 2; ++rs)
#pragma unroll
        for (int ct = 0; ct < 4; ++ct) acc[rs][ct] = {0.f, 0.f, 0.f, 0.f};

#pragma unroll
    for (int ks = 0; ks < 8; ++ks) {
        f16x8 qa0 = *(const f16x8*)(Qs + lr * 264 + ks * 32 + lg * 8);
        f16x8 qa1 = *(const f16x8*)(Qs + (16 + lr) * 264 + ks * 32 + lg * 8);
#pragma unroll
        for (int ct = 0; ct < 4; ++ct) {
            f16x8 bf = *(const f16x8*)(Kb + (size_t)(m0 + ct * 16 + lr) * CDIM + ks * 32 + lg * 8);
            acc[0][ct] = MFMA16(qa0, bf, acc[0][ct]);
            acc[1][ct] = MFMA16(qa1, bf, acc[1][ct]);
        }
    }

    float zs[2][4] = {{0.f, 0.f, 0.f, 0.f}, {0.f, 0.f, 0.f, 0.f}};
#pragma unroll
    for (int rs = 0; rs < 2; ++rs)
#pragma unroll
        for (int ct = 0; ct < 4; ++ct)
#pragma unroll
            for (int reg = 0; reg < 4; ++reg) {
                int row32 = rs * 16 + lg * 4 + reg;
                float e = __expf(acc[rs][ct][reg] - SHIFT);
                zs[rs][reg] += e;
                if (m0 + ct * 16 + lr == n0 + row32)
                    ediag[b * NPIX + n0 + row32] = e;
            }
#pragma unroll
    for (int rs = 0; rs < 2; ++rs)
#pragma unroll
        for (int reg = 0; reg < 4; ++reg) {
            float v = zs[rs][reg];
            v += __shfl_xor(v, 1);
            v += __shfl_xor(v, 2);
            v += __shfl_xor(v, 4);
            v += __shfl_xor(v, 8);
            zs[rs][reg] = v;
        }
    if (lr == 0)
#pragma unroll
        for (int rs = 0; rs < 2; ++rs)
#pragma unroll
            for (int reg = 0; reg < 4; ++reg)
                zpart[w][rs * 16 + lg * 4 + reg] = zs[rs][reg];
    __syncthreads();
    if (tid < 32) {
        float Zp = zpart[0][tid] + zpart[1][tid] + zpart[2][tid] + zpart[3][tid];
        atomicAdd(&Zbuf[b * NPIX + n0 + tid], Zp);
    }
}

// ---------------------------------------------------------------------------
// filter v3: same 8-chain sweep (bitwise-identical MFMA), threshold, append to
// per-block LDS lists, then one global atomicAdd per row reserves a range.
// mc==0, w==0 blocks also produce diagT.
// ---------------------------------------------------------------------------
__global__ __launch_bounds__(256) void filter_kernel(const f16* __restrict__ Qh,
                                                     const f16* __restrict__ Kh,
                                                     const float* __restrict__ Zbuf,
                                                     const float* __restrict__ ediag,
                                                     float* __restrict__ diagT,
                                                     unsigned* __restrict__ lists,
                                                     int* __restrict__ cnts) {
    __shared__ f16 Qs[32 * 264];
    __shared__ float invZ_s[32];
    __shared__ float thr_s[32];
    __shared__ int cnt_s[32];
    __shared__ int gbase[32];
    __shared__ unsigned list_s[32][LISTCAP];   // 13.3 KB
    int bid = blockIdx.x;
    int b = bid & 7;
    int r = bid >> 3;
    int mc = r / 72;
    int n0 = (r % 72) * 32;
    int tid = threadIdx.x;
    int l = tid & 63, w = tid >> 6;
    int lr = l & 15, lg = l >> 4;
    const f16* Qb = Qh + (size_t)b * NPIX * CDIM;
    const f16* Kb = Kh + (size_t)b * NPIX * CDIM;

    if (tid < 32) cnt_s[tid] = 0;
#pragma unroll
    for (int rep = 0; rep < 4; ++rep) {
        int idx = rep * 256 + tid;
        int row = idx >> 5, seg = idx & 31;
        *(f16x8*)(Qs + row * 264 + seg * 8) =
            *(const f16x8*)(Qb + (size_t)(n0 + row) * CDIM + seg * 8);
    }
    if (tid >= 32 && tid < 64) {
        int t = tid - 32;
        int n = b * NPIX + n0 + t;
        float Z = Zbuf[n];
        invZ_s[t] = 1.0f / Z;
        thr_s[t] = logf(THRESH) + logf(Z) - 1e-3f;   // log(0.01*Z) - slack
        if (mc == 0) {
            float d = ediag[n] * invZ_s[t];
            diagT[n] = (d < THRESH) ? 0.0f : d;
        }
    }
    __syncthreads();

    int m0 = (mc * 4 + w) * 64;
    f32x4 acc[2][4];
#pragma unroll
    for (int rs = 0; rs < 2; ++rs)
#pragma unroll
        for (int ct = 0; ct < 4; ++ct) acc[rs][ct] = {0.f, 0.f, 0.f, 0.f};

#pragma unroll
    for (int ks = 0; ks < 8; ++ks) {
        f16x8 qa0 = *(const f16x8*)(Qs + lr * 264 + ks * 32 + lg * 8);
        f16x8 qa1 = *(const f16x8*)(Qs + (16 + lr) * 264 + ks * 32 + lg * 8);
#pragma unroll
        for (int ct = 0; ct < 4; ++ct) {
            f16x8 bf = *(const f16x8*)(Kb + (size_t)(m0 + ct * 16 + lr) * CDIM + ks * 32 + lg * 8);
            acc[0][ct] = MFMA16(qa0, bf, acc[0][ct]);
            acc[1][ct] = MFMA16(qa1, bf, acc[1][ct]);
        }
    }

#pragma unroll
    for (int rs = 0; rs < 2; ++rs)
#pragma unroll
        for (int ct = 0; ct < 4; ++ct)
#pragma unroll
            for (int reg = 0; reg < 4; ++reg) {
                int row32 = rs * 16 + lg * 4 + reg;
                float lm = acc[rs][ct][reg] - SHIFT;
                if (lm >= thr_s[row32]) {
                    float s = __expf(lm) * invZ_s[row32];
                    if (s >= THRESH) {
                        int idx = atomicAdd(&cnt_s[row32], 1);
                        if (idx < LISTCAP)
                            list_s[row32][idx] =
                                ((unsigned)(m0 + ct * 16 + lr) << 16) | f16bits((f16)s);
                    }
                }
            }
    __syncthreads();
    if (tid < 32) {
        int c = cnt_s[tid];
        if (c > LISTCAP) c = LISTCAP;
        cnt_s[tid] = c;
        gbase[tid] = atomicAdd(&cnts[b * NPIX + n0 + tid], c);
    }
    __syncthreads();
    for (int i = tid; i < 32 * LISTCAP; i += 256) {
        int row = i / LISTCAP, j = i - row * LISTCAP;
        if (j < cnt_s[row]) {
            int n = b * NPIX + n0 + row;
            int dstidx = gbase[row] + j;
            if (dstidx < LISTCAP)
                lists[(size_t)n * LISTCAP + dstidx] = list_s[row][j];
        }
    }
}

// ---------------------------------------------------------------------------
// sparse (fused stencil): nbrH[n][c] = sum_k s_k*Xh[m_k][c] + stencil(Xh)[n][c]
//                                       - diagT[n]*Xh[n][c]
// 1-D grid 576 (b = bid&7 -> XCD pinned); 8 threads/row, 32 cols each, f16x8.
// ---------------------------------------------------------------------------
__global__ __launch_bounds__(256) void sparse_kernel(const unsigned* __restrict__ lists,
                                                     const int* __restrict__ cnts,
                                                     const f16* __restrict__ Xh,
                                                     const float* __restrict__ diagT,
                                                     f16* __restrict__ nbrH) {
    int bid = blockIdx.x;
    int b = bid & 7;
    int n0 = (bid >> 3) * 32;
    int tid = threadIdx.x;
    int r = tid >> 3, t8 = tid & 7;
    int n = n0 + r;
    const f16* Xb = Xh + (size_t)b * NPIX * CDIM;
    int k = cnts[b * NPIX + n];
    if (k > LISTCAP) k = LISTCAP;
    const unsigned* lrow = lists + (size_t)(b * NPIX + n) * LISTCAP;

    float accv[32];
#pragma unroll
    for (int j = 0; j < 32; ++j) accv[j] = 0.f;

    auto addrow = [&](int m, float s) {
        const f16* xr = Xb + (size_t)m * CDIM + t8 * 32;
#pragma unroll
        for (int v4 = 0; v4 < 4; ++v4) {
            f16x8 xv = *(const f16x8*)(xr + v4 * 8);
#pragma unroll
            for (int j = 0; j < 8; ++j) accv[v4 * 8 + j] += s * (float)xv[j];
        }
    };

    int hh = n / HWDIM, ww = n % HWDIM;
    if (hh > 0)         addrow(n - HWDIM, 1.0f);
    if (hh < HWDIM - 1) addrow(n + HWDIM, 1.0f);
    if (ww > 0)         addrow(n - 1, 1.0f);
    if (ww < HWDIM - 1) addrow(n + 1, 1.0f);
    addrow(n, -diagT[b * NPIX + n]);

    for (int i = 0; i < k; ++i) {
        unsigned pk = lrow[i];
        addrow((int)(pk >> 16), (float)bits2f16((unsigned short)(pk & 0xffffu)));
    }

    f16* orow = nbrH + ((size_t)b * NPIX + n) * CDIM + t8 * 32;
#pragma unroll
    for (int v4 = 0; v4 < 4; ++v4) {
        f16x8 ov;
#pragma unroll
        for (int j = 0; j < 8; ++j) ov[j] = (f16)accv[v4 * 8 + j];
        *(f16x8*)(orow + v4 * 8) = ov;
    }
}

// ---------------------------------------------------------------------------
// final: out[b][d][n] = relu( (1+diagT[n])·(Xh·w0ᵀ)[n][d] + (nbrH·w1ᵀ)[n][d] )
// 1-D grid 288 (b = bid&7 -> XCD pinned).
// ---------------------------------------------------------------------------
__global__ __launch_bounds__(256) void final_kernel(const f16* __restrict__ Xh,
                                                    const f16* __restrict__ nbrH,
                                                    const f16* __restrict__ wH,
                                                    const float* __restrict__ diagT,
                                                    float* __restrict__ out) {
    int bid = blockIdx.x;
    int b = bid & 7;
    int n0 = (bid >> 3) * 64;
    int tid = threadIdx.x;
    int l = tid & 63, w = tid >> 6;
    int wr = w >> 1, dw = w & 1;
    int lr = l & 15, lg = l >> 4;
    const f16* Xb = Xh + (size_t)b * NPIX * CDIM;
    const f16* Nb = nbrH + (size_t)b * NPIX * CDIM;
    const f16* w0H = wH + 2 * CDIM * CDIM;
    const f16* w1H = wH + 3 * CDIM * CDIM;

    f32x4 acc[2][8];
#pragma unroll
    for (int rs = 0; rs < 2; ++rs)
#pragma unroll
        for (int dt = 0; dt < 8; ++dt) acc[rs][dt] = {0.f, 0.f, 0.f, 0.f};

#pragma unroll
    for (int ks = 0; ks < 8; ++ks) {
        f16x8 a0 = *(const f16x8*)(Xb + (size_t)(n0 + wr * 32 + lr) * CDIM + ks * 32 + lg * 8);
        f16x8 a1 = *(const f16x8*)(Xb + (size_t)(n0 + wr * 32 + 16 + lr) * CDIM + ks * 32 + lg * 8);
#pragma unroll
        for (int dt = 0; dt < 8; ++dt) {
            f16x8 bf = *(const f16x8*)(w0H + (size_t)(dw * 128 + dt * 16 + lr) * CDIM + ks * 32 + lg * 8);
            acc[0][dt] = MFMA16(a0, bf, acc[0][dt]);
            acc[1][dt] = MFMA16(a1, bf, acc[1][dt]);
        }
    }
#pragma unroll
    for (int rs = 0; rs < 2; ++rs)
#pragma unroll
        for (int reg = 0; reg < 4; ++reg) {
            int n = n0 + wr * 32 + rs * 16 + lg * 4 + reg;
            float s = 1.0f + diagT[b * NPIX + n];
#pragma unroll
            for (int dt = 0; dt < 8; ++dt) acc[rs][dt][reg] *= s;
        }
#pragma unroll
    for (int ks = 0; ks < 8; ++ks) {
        f16x8 a0 = *(const f16x8*)(Nb + (size_t)(n0 + wr * 32 + lr) * CDIM + ks * 32 + lg * 8);
        f16x8 a1 = *(const f16x8*)(Nb + (size_t)(n0 + wr * 32 + 16 + lr) * CDIM + ks * 32 + lg * 8);
#pragma unroll
        for (int dt = 0; dt < 8; ++dt) {
            f16x8 bf = *(const f16x8*)(w1H + (size_t)(dw * 128 + dt * 16 + lr) * CDIM + ks * 32 + lg * 8);
            acc[0][dt] = MFMA16(a0, bf, acc[0][dt]);
            acc[1][dt] = MFMA16(a1, bf, acc[1][dt]);
        }
    }
#pragma unroll
    for (int rs = 0; rs < 2; ++rs)
#pragma unroll
        for (int dt = 0; dt < 8; ++dt) {
            int d = dw * 128 + dt * 16 + lr;
            int nb_ = n0 + wr * 32 + rs * 16 + lg * 4;
            f32x4 v = acc[rs][dt];
#pragma unroll
            for (int reg = 0; reg < 4; ++reg) v[reg] = fmaxf(v[reg], 0.0f);
            *(f32x4*)(out + ((size_t)b * CDIM + d) * NPIX + nb_) = v;
        }
}

extern "C" void kernel_launch(void* const* d_in, const int* in_sizes, int n_in,
                              void* d_out, int out_size, void* d_ws, size_t ws_size,
                              hipStream_t stream) {
    const float* x   = (const float*)d_in[0];
    const float* phi = (const float*)d_in[1];
    const float* psi = (const float*)d_in[2];
    const float* w0  = (const float*)d_in[3];
    const float* w1  = (const float*)d_in[4];
    float* out = (float*)d_out;

    const size_t BNC = (size_t)BATCH * NPIX * CDIM;
    const size_t BN  = (size_t)BATCH * NPIX;
    char* p = (char*)d_ws;
    auto alloc = [&](size_t bytes) { char* r = p; p += (bytes + 255) & ~(size_t)255; return r; };
    f16*      Xh    = (f16*)alloc(BNC * 2);
    f16*      Qh    = (f16*)alloc(BNC * 2);
    f16*      Kh    = (f16*)alloc(BNC * 2);
    f16*      nbrH  = (f16*)alloc(BNC * 2);
    f16*      wH    = (f16*)alloc((size_t)4 * CDIM * CDIM * 2);
    float*    Zbuf  = (float*)alloc(BN * 4);
    float*    ediag = (float*)alloc(BN * 4);
    float*    diagT = (float*)alloc(BN * 4);
    unsigned* lists = (unsigned*)alloc(BN * LISTCAP * 4);   // 7.7 MB
    int*      cnts  = (int*)alloc(BN * 4);

    prep_kernel<<<dim3(72, 8, 9), 256, 0, stream>>>(x, phi, psi, w0, w1, Xh, wH, Zbuf, cnts);
    proj_kernel<<<dim3(576), 256, 0, stream>>>(Xh, wH, Qh, Kh);
    zpass_kernel<<<dim3(5184), 256, 0, stream>>>(Qh, Kh, Zbuf, ediag);
    filter_kernel<<<dim3(5184), 256, 0, stream>>>(Qh, Kh, Zbuf, ediag, diagT, lists, cnts);
    sparse_kernel<<<dim3(576), 256, 0, stream>>>(lists, cnts, Xh, diagT, nbrH);
    final_kernel<<<dim3(288), 256, 0, stream>>>(Xh, nbrH, wH, diagT, out);
}